// Round 12
// baseline (448.823 us; speedup 1.0000x reference)
//
#include <hip/hip_runtime.h>
#include <hip/hip_cooperative_groups.h>
#include <cstddef>

namespace cg = cooperative_groups;

typedef _Float16 f16;
typedef __attribute__((ext_vector_type(4))) _Float16 f16x4;
typedef __attribute__((ext_vector_type(8))) _Float16 f16x8;
typedef __attribute__((ext_vector_type(4))) float f32x4;

namespace {
constexpr int kB = 16;
constexpr int kN = 2048;
constexpr int kD = 256;   // D_IN
constexpr int kC = 32;
constexpr int kH = 64;
constexpr int kHeads = 4;
constexpr int kKD = 64;
constexpr int kChunks = 32;                  // n-chunks per b (64 rows each)
constexpr int kRows = kN / kChunks;          // 64
constexpr int kXJ = 64;                      // fallback xpart sub-chunks (32 rows)

// workspace offsets (floats) — round-10 layout
constexpr size_t OFF_XPART = 0;                       // [B,64,D]         262144
constexpr size_t OFF_V     = OFF_XPART + 262144;      // [B,C,H]           32768
constexpr size_t OFF_WV    = OFF_V + 32768;           // [B,C,D] fp32     131072
constexpr size_t OFF_BV    = OFF_WV + 131072;         // [B,C]               512
constexpr size_t OFF_Y     = OFF_BV + 512;            // [B,C,D] (atomic) 131072
constexpr size_t OFF_CS    = OFF_Y + 131072;          // [B,C]               512
constexpr size_t OFF_QKV   = OFF_CS + 512;            // [3,B,H,C,KD]     393216
constexpr size_t OFF_CTX   = OFF_QKV + 393216;        // [B,C,HEADS,KD]   524288
constexpr size_t OFF_XF16  = OFF_CTX + 524288;        // [B,N,D] f16     4194304
constexpr size_t OFF_WVH   = OFF_XF16 + 4194304;      // [B,C,D] f16       65536
constexpr size_t OFF_CSP   = OFF_WVH + 65536;         // [B,chunks,C]      16384
constexpr size_t OFF_YP    = OFF_CSP + 16384;         // [B,chunks,C,D]  4194304
constexpr size_t WS_NEED_PARTIAL = (OFF_YP + 4194304) * sizeof(float);

struct SMemRoute {
  f16 xsT[kD][kRows + 8];     // 36864 B
  float aL[kRows][kC + 4];    //  9216 B
  f16 pT[kC][kRows + 8];      //  4608 B
  float csL[8][kC];           //  1024 B
};
struct SMemSv {
  float yL[kD];
  float sL[4][kH];
  float vL[kH];
  float csLs;
};
struct SMemAttn {
  float qL[kC][kKD];
  float kL[kC][kKD + 1];
  float vL[kC][kKD];
  float sc[kC][kC + 1];
};
struct SMemMisc {
  float rL[kC * kH];
  float red[4][kD];
  float sL2[4][kH];
};
union SMemU {
  SMemRoute r;
  SMemSv s;
  SMemAttn a;
  SMemMisc m;
};
}  // namespace

// ======================= coop device phases =======================

// sv phase (coop): xpart layout [B,32,D].
__device__ __forceinline__ void sv_phase(
    SMemU& sm, const int b, const int c, const int t,
    const float* __restrict__ W, const float* __restrict__ b_caps,
    const float* __restrict__ xpart, const float* __restrict__ ypart,
    const float* __restrict__ cspart, float* __restrict__ v,
    float* __restrict__ Wv, f16* __restrict__ Wvh, float* __restrict__ bv,
    const int mode, const int computeWv, const int accWv) {
  __syncthreads();  // protect LDS reuse across phase-loop iterations
  const int bc = b * kC + c;
  const int w = t >> 6, h = t & 63;
  if (mode == 0) {
    float s = 0.f;
#pragma unroll 8
    for (int j = 0; j < kChunks; ++j) s += xpart[((size_t)b * kChunks + j) * kD + t];
    sm.s.yL[t] = s * (1.f / (float)kC);
    if (t == 0) sm.s.csLs = (float)kN / (float)kC;
  } else {
    float s = 0.f;
#pragma unroll 8
    for (int ch = 0; ch < kChunks; ++ch)
      s += ypart[(((size_t)b * kChunks + ch) * kC + c) * kD + t];
    sm.s.yL[t] = s;
    if (t < 32) {
      float cs_ = cspart[((size_t)b * kChunks + t) * kC + c];
#pragma unroll
      for (int off = 16; off; off >>= 1) cs_ += __shfl_xor(cs_, off, 64);
      if (t == 0) sm.s.csLs = cs_;
    }
  }
  __syncthreads();
  const float* Wc = W + (size_t)c * kD * kH;
  {
    float acc = 0.f;
#pragma unroll 8
    for (int d = w * 64; d < (w + 1) * 64; ++d)
      acc = fmaf(sm.s.yL[d], Wc[(size_t)d * kH + h], acc);
    sm.s.sL[w][h] = acc;
  }
  __syncthreads();
  if (t < 64) {
    const float bch = b_caps[c * kH + h];
    float s = sm.s.sL[0][h] + sm.s.sL[1][h] + sm.s.sL[2][h] + sm.s.sL[3][h] +
              sm.s.csLs * bch;
    float s2 = s * s;
#pragma unroll
    for (int off = 32; off; off >>= 1) s2 += __shfl_xor(s2, off, 64);
    const float scale = s2 / (1.f + s2) * rsqrtf(s2 + 1e-7f);
    const float vh = scale * s;
    v[(size_t)bc * kH + h] = vh;
    sm.s.vL[h] = vh;
    if (computeWv) {
      float bvp = bch * vh;
#pragma unroll
      for (int off = 32; off; off >>= 1) bvp += __shfl_xor(bvp, off, 64);
      if (h == 0) bv[bc] = accWv ? (bv[bc] + bvp) : bvp;
    }
  }
  __syncthreads();
  if (computeWv) {
    float acc = 0.f;
    const float* Wrow = Wc + (size_t)t * kH;
#pragma unroll 8
    for (int hh = 0; hh < kH; ++hh) acc = fmaf(Wrow[hh], sm.s.vL[hh], acc);
    const size_t idx = (size_t)bc * kD + t;
    const float nv = accWv ? (Wv[idx] + acc) : acc;
    Wv[idx] = nv;
    Wvh[idx] = (f16)nv;
  }
}

// route phase (coop): round-8 verified MFMA body, partials flush.
__device__ __forceinline__ void route_phase(
    SMemU& sm, const int b, const int chunk, const int t,
    const f16* __restrict__ xh, const f16* __restrict__ Wvh,
    const float* __restrict__ bv, float* __restrict__ ypart,
    float* __restrict__ cspart) {
  __syncthreads();  // protect LDS reuse across phase-loop iterations
  const int lane = t & 63, w = t >> 6;
  const int l15 = lane & 15, q = lane >> 4;
  const int n0 = chunk * kRows;
  const float bvc = bv[b * kC + (t & 31)];

  f32x4 acc0 = {0.f, 0.f, 0.f, 0.f}, acc1 = {0.f, 0.f, 0.f, 0.f};
  {
    const int row = w * 16 + l15;
    const f16x8* Ar = reinterpret_cast<const f16x8*>(
        xh + ((size_t)(b * kN + n0 + row)) * kD + q * 8);
    const f16x8* B0 = reinterpret_cast<const f16x8*>(
        Wvh + ((size_t)(b * kC + l15)) * kD + q * 8);
    const f16x8* B1 = reinterpret_cast<const f16x8*>(
        Wvh + ((size_t)(b * kC + 16 + l15)) * kD + q * 8);
#pragma unroll
    for (int ks = 0; ks < 8; ++ks) {
      f16x8 af = Ar[ks * 4];
      acc0 = __builtin_amdgcn_mfma_f32_16x16x32_f16(af, B0[ks * 4], acc0, 0, 0, 0);
      acc1 = __builtin_amdgcn_mfma_f32_16x16x32_f16(af, B1[ks * 4], acc1, 0, 0, 0);
      const int dbase = ks * 32 + q * 8;
#pragma unroll
      for (int i = 0; i < 8; ++i) {
        const int ii = (i + 2 * q) & 7;  // rotate: distinct banks across q-groups
        sm.r.xsT[dbase + ii][row] = af[ii];
      }
    }
  }
#pragma unroll
  for (int r = 0; r < 4; ++r) {
    sm.r.aL[w * 16 + q * 4 + r][l15] = acc0[r];
    sm.r.aL[w * 16 + q * 4 + r][16 + l15] = acc1[r];
  }
  __syncthreads();

  const int c = t & 31, sg = t >> 5;
  float csreg = 0.f;
#pragma unroll
  for (int k = 0; k < 8; ++k) {
    const int r = sg * 8 + k;
    float L = bvc + sm.r.aL[r][c];
    float m = L;
#pragma unroll
    for (int off = 16; off; off >>= 1) m = fmaxf(m, __shfl_xor(m, off, 64));
    const float e = __expf(L - m);
    float ssum = e;
#pragma unroll
    for (int off = 16; off; off >>= 1) ssum += __shfl_xor(ssum, off, 64);
    const float p = e / ssum;
    sm.r.pT[c][r] = (f16)p;
    csreg += p;
  }
  sm.r.csL[sg][c] = csreg;
  __syncthreads();

  const int mt2 = w & 1;
  const int ntb = (w >> 1) * 8;
  const f16x8 a0 = *reinterpret_cast<const f16x8*>(&sm.r.pT[mt2 * 16 + l15][q * 8]);
  const f16x8 a1 = *reinterpret_cast<const f16x8*>(&sm.r.pT[mt2 * 16 + l15][32 + q * 8]);
  const int cap = mt2 * 16 + q * 4;
#pragma unroll
  for (int i = 0; i < 8; ++i) {
    const int d0 = (ntb + i) * 16;
    const f16x8 b0 = *reinterpret_cast<const f16x8*>(&sm.r.xsT[d0 + l15][q * 8]);
    const f16x8 b1 = *reinterpret_cast<const f16x8*>(&sm.r.xsT[d0 + l15][32 + q * 8]);
    f32x4 o = {0.f, 0.f, 0.f, 0.f};
    o = __builtin_amdgcn_mfma_f32_16x16x32_f16(a0, b0, o, 0, 0, 0);
    o = __builtin_amdgcn_mfma_f32_16x16x32_f16(a1, b1, o, 0, 0, 0);
    float* dst = ypart + (((size_t)(b * kChunks + chunk)) * kC + cap) * kD + d0 + l15;
#pragma unroll
    for (int r = 0; r < 4; ++r) dst[(size_t)r * kD] = o[r];
  }
  if (t < 32) {
    float s = 0.f;
#pragma unroll
    for (int j = 0; j < 8; ++j) s += sm.r.csL[j][t];
    cspart[((size_t)b * kChunks + chunk) * kC + t] = s;
  }
}

// ---- the whole pipeline, one cooperative kernel. grid = 256 (1 block/CU).
__global__ __launch_bounds__(256) void k_caps(
    const float* __restrict__ x, const float* __restrict__ W,
    const float* __restrict__ b_caps, const float* __restrict__ Wq,
    const float* __restrict__ bq, const float* __restrict__ Wk,
    const float* __restrict__ bk, const float* __restrict__ Wvp,
    const float* __restrict__ bvp, const float* __restrict__ Wo,
    const float* __restrict__ bo, const float* __restrict__ ln_g,
    const float* __restrict__ ln_b, const float* __restrict__ gamma,
    float* __restrict__ xpart, float* __restrict__ v, float* __restrict__ Wv,
    f16* __restrict__ Wvh, float* __restrict__ bv, f16* __restrict__ xh,
    float* __restrict__ ypart, float* __restrict__ cspart,
    float* __restrict__ qkv, float* __restrict__ ctx, float* __restrict__ out) {
  cg::grid_group grid = cg::this_grid();
  __shared__ __align__(16) SMemU sm;
  const int blk = blockIdx.x;          // 0..255
  const int b = blk >> 4, g16 = blk & 15;
  const int t = threadIdx.x;

  // ---- A: fp16 convert + partial column sums; 2 chunks of 64 rows per block
  for (int u = 0; u < 2; ++u) {
    __syncthreads();
    const int chunk = g16 * 2 + u;
    const int rg = t >> 6, dq = t & 63;
    float4 s = {0.f, 0.f, 0.f, 0.f};
    const size_t rowbase = (size_t)b * kN + (size_t)chunk * kRows;
#pragma unroll
    for (int i = 0; i < 16; ++i) {
      const int r = rg * 16 + i;
      const float4 qv = *(reinterpret_cast<const float4*>(x + (rowbase + r) * kD) + dq);
      s.x += qv.x; s.y += qv.y; s.z += qv.z; s.w += qv.w;
      f16x4 h4 = {(f16)qv.x, (f16)qv.y, (f16)qv.z, (f16)qv.w};
      *(reinterpret_cast<f16x4*>(xh + (rowbase + r) * kD) + dq) = h4;
    }
    reinterpret_cast<float4*>(&sm.m.red[rg][0])[dq] = s;
    __syncthreads();
    xpart[((size_t)b * kChunks + chunk) * kD + t] =
        sm.m.red[0][t] + sm.m.red[1][t] + sm.m.red[2][t] + sm.m.red[3][t];
  }
  grid.sync();
  // ---- B: sv0 (uniform coupling); 2 capsules per block
  for (int u = 0; u < 2; ++u)
    sv_phase(sm, b, g16 * 2 + u, t, W, b_caps, xpart, ypart, cspart, v, Wv, Wvh,
             bv, /*mode=*/0, /*computeWv=*/1, /*accWv=*/0);
  grid.sync();
  // ---- C: routing pass 1; 2 chunks per block
  for (int u = 0; u < 2; ++u)
    route_phase(sm, b, g16 * 2 + u, t, xh, Wvh, bv, ypart, cspart);
  grid.sync();
  // ---- D: sv1 (accumulate Wv: logits2 = u·(v0+v1))
  for (int u = 0; u < 2; ++u)
    sv_phase(sm, b, g16 * 2 + u, t, W, b_caps, xpart, ypart, cspart, v, Wv, Wvh,
             bv, /*mode=*/1, /*computeWv=*/1, /*accWv=*/1);
  grid.sync();
  // ---- E: routing pass 2
  for (int u = 0; u < 2; ++u)
    route_phase(sm, b, g16 * 2 + u, t, xh, Wvh, bv, ypart, cspart);
  grid.sync();
  // ---- F: sv2 -> final routed v
  for (int u = 0; u < 2; ++u)
    sv_phase(sm, b, g16 * 2 + u, t, W, b_caps, xpart, ypart, cspart, v, Wv, Wvh,
             bv, /*mode=*/1, /*computeWv=*/0, /*accWv=*/0);
  grid.sync();
  // ---- G: qkv projections (192 active blocks)
  if (blk < 192) {
    const int which = blk >> 6, rem = blk & 63;
    const int b2 = rem >> 2, head = rem & 3;
    const int kk = t & 63, w2 = t >> 6;
    const float* Wsrc = (which == 0) ? Wq : (which == 1) ? Wk : Wvp;
    const float* bsrc = (which == 0) ? bq : (which == 1) ? bk : bvp;
#pragma unroll
    for (int i = 0; i < 8; ++i)
      sm.m.rL[t + 256 * i] = v[(size_t)b2 * kC * kH + t + 256 * i];
    __syncthreads();
    float acc[8];
    const float bb = bsrc[head * kKD + kk];
#pragma unroll
    for (int i = 0; i < 8; ++i) acc[i] = bb;
#pragma unroll 4
    for (int hh = 0; hh < kH; ++hh) {
      const float wv = Wsrc[((size_t)hh * kHeads + head) * kKD + kk];
#pragma unroll
      for (int i = 0; i < 8; ++i)
        acc[i] = fmaf(sm.m.rL[(w2 + 4 * i) * kH + hh], wv, acc[i]);
    }
#pragma unroll
    for (int i = 0; i < 8; ++i) {
      const int cc = w2 + 4 * i;
      qkv[((((size_t)which * kB + b2) * kHeads + head) * kC + cc) * kKD + kk] = acc[i];
    }
  }
  grid.sync();
  // ---- H: attention scores/softmax/ctx (64 active blocks)
  if (blk < 64) {
    const int b2 = blk >> 2, head = blk & 3;
    constexpr size_t kWhichStride = (size_t)kB * kHeads * kC * kKD;
    const size_t base = ((size_t)b2 * kHeads + head) * kC * kKD;
#pragma unroll
    for (int i = 0; i < 8; ++i) {
      const int e = t + 256 * i, cc = e >> 6, kk = e & 63;
      sm.a.qL[cc][kk] = qkv[base + e];
      sm.a.kL[cc][kk] = qkv[base + kWhichStride + e];
      sm.a.vL[cc][kk] = qkv[base + 2 * kWhichStride + e];
    }
    __syncthreads();
#pragma unroll
    for (int i = 0; i < 4; ++i) {
      const int e = t + 256 * i, qc = e >> 5, kc = e & 31;
      float s = 0.f;
#pragma unroll 8
      for (int d = 0; d < kKD; ++d) s = fmaf(sm.a.qL[qc][d], sm.a.kL[kc][d], s);
      sm.a.sc[qc][kc] = s * 0.125f;  // 1/sqrt(64)
    }
    __syncthreads();
    if (t < kC) {
      float m = -1e30f;
#pragma unroll
      for (int kc = 0; kc < kC; ++kc) m = fmaxf(m, sm.a.sc[t][kc]);
      float ssum = 0.f;
#pragma unroll
      for (int kc = 0; kc < kC; ++kc) {
        const float e2 = __expf(sm.a.sc[t][kc] - m);
        sm.a.sc[t][kc] = e2;
        ssum += e2;
      }
      const float inv = 1.f / ssum;
#pragma unroll
      for (int kc = 0; kc < kC; ++kc) sm.a.sc[t][kc] *= inv;
    }
    __syncthreads();
#pragma unroll
    for (int i = 0; i < 8; ++i) {
      const int e = t + 256 * i, qc = e >> 6, d = e & 63;
      float s = 0.f;
#pragma unroll 8
      for (int kc = 0; kc < kC; ++kc) s = fmaf(sm.a.sc[qc][kc], sm.a.vL[kc][d], s);
      ctx[(((size_t)b2 * kC + qc) * kHeads + head) * kKD + d] = s;
    }
  }
  grid.sync();
  // ---- I: out-proj + residual + LN + squash*gamma; 2 bc per block
  for (int u = 0; u < 2; ++u) {
    __syncthreads();
    const int bc = blk * 2 + u;
    const int w2 = t >> 6, h = t & 63;
    sm.m.rL[t] = ctx[(size_t)bc * (kHeads * kKD) + t];
    __syncthreads();
    float acc = 0.f;
#pragma unroll 8
    for (int nd = w2 * 64; nd < (w2 + 1) * 64; ++nd)
      acc = fmaf(sm.m.rL[nd], Wo[(size_t)nd * kH + h], acc);
    sm.m.sL2[w2][h] = acc;
    __syncthreads();
    if (t < 64) {
      const float yv = sm.m.sL2[0][h] + sm.m.sL2[1][h] + sm.m.sL2[2][h] +
                       sm.m.sL2[3][h] + bo[h] + v[(size_t)bc * kH + h];
      float mu = yv;
#pragma unroll
      for (int off = 32; off; off >>= 1) mu += __shfl_xor(mu, off, 64);
      mu *= (1.f / (float)kH);
      const float dv = yv - mu;
      float var = dv * dv;
#pragma unroll
      for (int off = 32; off; off >>= 1) var += __shfl_xor(var, off, 64);
      var *= (1.f / (float)kH);
      const float nrm = dv * rsqrtf(var + 1e-3f) * ln_g[h] + ln_b[h];
      float s2 = nrm * nrm;
#pragma unroll
      for (int off = 32; off; off >>= 1) s2 += __shfl_xor(s2, off, 64);
      const float scale = s2 / (1.f + s2) * rsqrtf(s2 + 1e-7f);
      out[(size_t)bc * kH + h] = scale * nrm * gamma[0];
    }
  }
}

// ======================= fallback kernels (round-10 verbatim) =======================

__global__ __launch_bounds__(256) void k_xpart(const float* __restrict__ x,
                                               float* __restrict__ xpart,
                                               f16* __restrict__ xh) {
  const int b = blockIdx.x, j = blockIdx.y;
  const int t = threadIdx.x;
  const int rg = t >> 6, dq = t & 63;
  __shared__ float sL[4][kD];
  float4 s = {0.f, 0.f, 0.f, 0.f};
  const size_t rowbase = (size_t)b * kN + (size_t)j * 32;
#pragma unroll
  for (int i = 0; i < 8; ++i) {
    const int r = rg * 8 + i;
    const float4 q = *(reinterpret_cast<const float4*>(x + (rowbase + r) * kD) + dq);
    s.x += q.x; s.y += q.y; s.z += q.z; s.w += q.w;
    f16x4 h4 = {(f16)q.x, (f16)q.y, (f16)q.z, (f16)q.w};
    *(reinterpret_cast<f16x4*>(xh + (rowbase + r) * kD) + dq) = h4;
  }
  reinterpret_cast<float4*>(&sL[rg][0])[dq] = s;
  __syncthreads();
  const int d = t;
  xpart[((size_t)b * kXJ + j) * kD + d] =
      sL[0][d] + sL[1][d] + sL[2][d] + sL[3][d];
}

__global__ __launch_bounds__(256) void k_sv(
    const float* __restrict__ W, const float* __restrict__ b_caps,
    const float* __restrict__ xpart, const float* __restrict__ y,
    const float* __restrict__ csum, const float* __restrict__ ypart,
    const float* __restrict__ cspart, float* __restrict__ v,
    float* __restrict__ Wv, f16* __restrict__ Wvh, float* __restrict__ bv,
    const int mode, const int computeWv, const int accWv, const int npart) {
  const int bc = blockIdx.x, b = bc >> 5, c = bc & 31;
  const int t = threadIdx.x;
  const int w = t >> 6, h = t & 63;
  __shared__ float yL[kD];
  __shared__ float sL[4][kH];
  __shared__ float vL[kH];
  __shared__ float csLs;

  if (mode == 0) {
    float s = 0.f;
#pragma unroll 8
    for (int j = 0; j < kXJ; ++j) s += xpart[((size_t)b * kXJ + j) * kD + t];
    yL[t] = s * (1.f / (float)kC);
    if (t == 0) csLs = (float)kN / (float)kC;
  } else if (npart > 0) {
    float s = 0.f;
#pragma unroll 8
    for (int ch = 0; ch < kChunks; ++ch)
      s += ypart[(((size_t)b * kChunks + ch) * kC + c) * kD + t];
    yL[t] = s;
    if (t < 32) {
      float cs_ = cspart[((size_t)b * kChunks + t) * kC + c];
#pragma unroll
      for (int off = 16; off; off >>= 1) cs_ += __shfl_xor(cs_, off, 64);
      if (t == 0) csLs = cs_;
    }
  } else {
    yL[t] = y[(size_t)bc * kD + t];
    if (t == 0) csLs = csum[bc];
  }
  __syncthreads();

  const float* Wc = W + (size_t)c * kD * kH;
  {
    float acc = 0.f;
#pragma unroll 8
    for (int d = w * 64; d < (w + 1) * 64; ++d)
      acc = fmaf(yL[d], Wc[(size_t)d * kH + h], acc);
    sL[w][h] = acc;
  }
  __syncthreads();

  if (t < 64) {
    const float bch = b_caps[c * kH + h];
    float s = sL[0][h] + sL[1][h] + sL[2][h] + sL[3][h] + csLs * bch;
    float s2 = s * s;
#pragma unroll
    for (int off = 32; off; off >>= 1) s2 += __shfl_xor(s2, off, 64);
    const float scale = s2 / (1.f + s2) * rsqrtf(s2 + 1e-7f);
    const float vh = scale * s;
    v[(size_t)bc * kH + h] = vh;
    vL[h] = vh;
    if (computeWv) {
      float bvp = bch * vh;
#pragma unroll
      for (int off = 32; off; off >>= 1) bvp += __shfl_xor(bvp, off, 64);
      if (h == 0) bv[bc] = accWv ? (bv[bc] + bvp) : bvp;
    }
  }
  __syncthreads();
  if (computeWv) {
    float acc = 0.f;
    const float* Wrow = Wc + (size_t)t * kH;
#pragma unroll 8
    for (int hh = 0; hh < kH; ++hh) acc = fmaf(Wrow[hh], vL[hh], acc);
    const size_t idx = (size_t)bc * kD + t;
    const float nv = accWv ? (Wv[idx] + acc) : acc;
    Wv[idx] = nv;
    Wvh[idx] = (f16)nv;
  }
}

__global__ __launch_bounds__(256) void k_route(
    const f16* __restrict__ xh, const f16* __restrict__ Wvh,
    const float* __restrict__ bv, float* __restrict__ y,
    float* __restrict__ csum, float* __restrict__ ypart,
    float* __restrict__ cspart, const int usePart) {
  const int b = blockIdx.x, chunk = blockIdx.y;
  const int t = threadIdx.x;
  const int lane = t & 63, w = t >> 6;
  const int l15 = lane & 15, q = lane >> 4;

  __shared__ __align__(16) f16 xsT[kD][kRows + 8];
  __shared__ float aL[kRows][kC + 4];
  __shared__ __align__(16) f16 pT[kC][kRows + 8];
  __shared__ float csL[8][kC];

  const int n0 = chunk * kRows;
  const float bvc = bv[b * kC + (t & 31)];

  f32x4 acc0 = {0.f, 0.f, 0.f, 0.f}, acc1 = {0.f, 0.f, 0.f, 0.f};
  {
    const int row = w * 16 + l15;
    const f16x8* Ar = reinterpret_cast<const f16x8*>(
        xh + ((size_t)(b * kN + n0 + row)) * kD + q * 8);
    const f16x8* B0 = reinterpret_cast<const f16x8*>(
        Wvh + ((size_t)(b * kC + l15)) * kD + q * 8);
    const f16x8* B1 = reinterpret_cast<const f16x8*>(
        Wvh + ((size_t)(b * kC + 16 + l15)) * kD + q * 8);
#pragma unroll
    for (int ks = 0; ks < 8; ++ks) {
      f16x8 af = Ar[ks * 4];
      acc0 = __builtin_amdgcn_mfma_f32_16x16x32_f16(af, B0[ks * 4], acc0, 0, 0, 0);
      acc1 = __builtin_amdgcn_mfma_f32_16x16x32_f16(af, B1[ks * 4], acc1, 0, 0, 0);
      const int dbase = ks * 32 + q * 8;
#pragma unroll
      for (int i = 0; i < 8; ++i) {
        const int ii = (i + 2 * q) & 7;
        xsT[dbase + ii][row] = af[ii];
      }
    }
  }
#pragma unroll
  for (int r = 0; r < 4; ++r) {
    aL[w * 16 + q * 4 + r][l15] = acc0[r];
    aL[w * 16 + q * 4 + r][16 + l15] = acc1[r];
  }
  __syncthreads();

  const int c = t & 31, sg = t >> 5;
  float csreg = 0.f;
#pragma unroll
  for (int k = 0; k < 8; ++k) {
    const int r = sg * 8 + k;
    float L = bvc + aL[r][c];
    float m = L;
#pragma unroll
    for (int off = 16; off; off >>= 1) m = fmaxf(m, __shfl_xor(m, off, 64));
    const float e = __expf(L - m);
    float ssum = e;
#pragma unroll
    for (int off = 16; off; off >>= 1) ssum += __shfl_xor(ssum, off, 64);
    const float p = e / ssum;
    pT[c][r] = (f16)p;
    csreg += p;
  }
  csL[sg][c] = csreg;
  __syncthreads();

  const int mt2 = w & 1;
  const int ntb = (w >> 1) * 8;
  const f16x8 a0 = *reinterpret_cast<const f16x8*>(&pT[mt2 * 16 + l15][q * 8]);
  const f16x8 a1 = *reinterpret_cast<const f16x8*>(&pT[mt2 * 16 + l15][32 + q * 8]);
  const int cap = mt2 * 16 + q * 4;
#pragma unroll
  for (int i = 0; i < 8; ++i) {
    const int d0 = (ntb + i) * 16;
    const f16x8 b0 = *reinterpret_cast<const f16x8*>(&xsT[d0 + l15][q * 8]);
    const f16x8 b1 = *reinterpret_cast<const f16x8*>(&xsT[d0 + l15][32 + q * 8]);
    f32x4 o = {0.f, 0.f, 0.f, 0.f};
    o = __builtin_amdgcn_mfma_f32_16x16x32_f16(a0, b0, o, 0, 0, 0);
    o = __builtin_amdgcn_mfma_f32_16x16x32_f16(a1, b1, o, 0, 0, 0);
    if (usePart) {
      float* dst = ypart + (((size_t)(b * kChunks + chunk)) * kC + cap) * kD + d0 + l15;
#pragma unroll
      for (int r = 0; r < 4; ++r) dst[(size_t)r * kD] = o[r];
    } else {
      float* dst = y + ((size_t)(b * kC + cap)) * kD + d0 + l15;
#pragma unroll
      for (int r = 0; r < 4; ++r) atomicAdd(dst + (size_t)r * kD, o[r]);
    }
  }
  if (t < 32) {
    float s = 0.f;
#pragma unroll
    for (int j = 0; j < 8; ++j) s += csL[j][t];
    if (usePart) cspart[((size_t)b * kChunks + chunk) * kC + t] = s;
    else atomicAdd(csum + b * kC + t, s);
  }
}

__global__ __launch_bounds__(256) void k_qkv(
    const float* __restrict__ routed, const float* __restrict__ Wq,
    const float* __restrict__ bq, const float* __restrict__ Wk,
    const float* __restrict__ bk, const float* __restrict__ Wvp,
    const float* __restrict__ bvp, float* __restrict__ qkv) {
  const int b = blockIdx.x, head = blockIdx.y, which = blockIdx.z;
  const int t = threadIdx.x;
  const int kk = t & 63, w = t >> 6;
  const float* Wsrc = (which == 0) ? Wq : (which == 1) ? Wk : Wvp;
  const float* bsrc = (which == 0) ? bq : (which == 1) ? bk : bvp;
  __shared__ float rL[kC * kH];
#pragma unroll
  for (int i = 0; i < 8; ++i) rL[t + 256 * i] = routed[(size_t)b * kC * kH + t + 256 * i];
  __syncthreads();
  float acc[8];
  const float bb = bsrc[head * kKD + kk];
#pragma unroll
  for (int i = 0; i < 8; ++i) acc[i] = bb;
#pragma unroll 4
  for (int hh = 0; hh < kH; ++hh) {
    const float wv = Wsrc[((size_t)hh * kHeads + head) * kKD + kk];
#pragma unroll
    for (int i = 0; i < 8; ++i)
      acc[i] = fmaf(rL[(w + 4 * i) * kH + hh], wv, acc[i]);
  }
#pragma unroll
  for (int i = 0; i < 8; ++i) {
    const int cc = w + 4 * i;
    qkv[((((size_t)which * kB + b) * kHeads + head) * kC + cc) * kKD + kk] = acc[i];
  }
}

__global__ __launch_bounds__(256) void k_attn2(const float* __restrict__ qkv,
                                               float* __restrict__ ctx) {
  const int b = blockIdx.x, head = blockIdx.y, t = threadIdx.x;
  constexpr size_t kWhichStride = (size_t)kB * kHeads * kC * kKD;
  const size_t base = ((size_t)b * kHeads + head) * kC * kKD;
  __shared__ float qL[kC][kKD];
  __shared__ float kL[kC][kKD + 1];
  __shared__ float vL[kC][kKD];
  __shared__ float sc[kC][kC + 1];
#pragma unroll
  for (int i = 0; i < 8; ++i) {
    const int e = t + 256 * i, cc = e >> 6, kk = e & 63;
    qL[cc][kk] = qkv[base + e];
    kL[cc][kk] = qkv[base + kWhichStride + e];
    vL[cc][kk] = qkv[base + 2 * kWhichStride + e];
  }
  __syncthreads();
#pragma unroll
  for (int i = 0; i < 4; ++i) {
    const int e = t + 256 * i, qc = e >> 5, kc = e & 31;
    float s = 0.f;
#pragma unroll 8
    for (int d = 0; d < kKD; ++d) s = fmaf(qL[qc][d], kL[kc][d], s);
    sc[qc][kc] = s * 0.125f;
  }
  __syncthreads();
  if (t < kC) {
    float m = -1e30f;
#pragma unroll
    for (int kc = 0; kc < kC; ++kc) m = fmaxf(m, sc[t][kc]);
    float ssum = 0.f;
#pragma unroll
    for (int kc = 0; kc < kC; ++kc) {
      const float e2 = __expf(sc[t][kc] - m);
      sc[t][kc] = e2;
      ssum += e2;
    }
    const float inv = 1.f / ssum;
#pragma unroll
    for (int kc = 0; kc < kC; ++kc) sc[t][kc] *= inv;
  }
  __syncthreads();
#pragma unroll
  for (int i = 0; i < 8; ++i) {
    const int e = t + 256 * i, qc = e >> 6, d = e & 63;
    float s = 0.f;
#pragma unroll 8
    for (int kc = 0; kc < kC; ++kc) s = fmaf(sc[qc][kc], vL[kc][d], s);
    ctx[(((size_t)b * kC + qc) * kHeads + head) * kKD + d] = s;
  }
}

__global__ __launch_bounds__(256) void k_final(
    const float* __restrict__ ctx, const float* __restrict__ Wo,
    const float* __restrict__ bo, const float* __restrict__ routed,
    const float* __restrict__ ln_g, const float* __restrict__ ln_b,
    const float* __restrict__ gamma, float* __restrict__ out) {
  const int bc = blockIdx.x, t = threadIdx.x;
  const int w = t >> 6, h = t & 63;
  __shared__ float cL[kHeads * kKD];
  __shared__ float sL[4][kH];
  cL[t] = ctx[(size_t)bc * (kHeads * kKD) + t];
  __syncthreads();
  float acc = 0.f;
#pragma unroll 8
  for (int nd = w * 64; nd < (w + 1) * 64; ++nd)
    acc = fmaf(cL[nd], Wo[(size_t)nd * kH + h], acc);
  sL[w][h] = acc;
  __syncthreads();
  if (t < 64) {
    const float yv = sL[0][h] + sL[1][h] + sL[2][h] + sL[3][h] + bo[h] +
                     routed[(size_t)bc * kH + h];
    float mu = yv;
#pragma unroll
    for (int off = 32; off; off >>= 1) mu += __shfl_xor(mu, off, 64);
    mu *= (1.f / (float)kH);
    const float dv = yv - mu;
    float var = dv * dv;
#pragma unroll
    for (int off = 32; off; off >>= 1) var += __shfl_xor(var, off, 64);
    var *= (1.f / (float)kH);
    const float nrm = dv * rsqrtf(var + 1e-3f) * ln_g[h] + ln_b[h];
    float s2 = nrm * nrm;
#pragma unroll
    for (int off = 32; off; off >>= 1) s2 += __shfl_xor(s2, off, 64);
    const float scale = s2 / (1.f + s2) * rsqrtf(s2 + 1e-7f);
    out[(size_t)bc * kH + h] = scale * nrm * gamma[0];
  }
}

extern "C" void kernel_launch(void* const* d_in, const int* in_sizes, int n_in,
                              void* d_out, int out_size, void* d_ws, size_t ws_size,
                              hipStream_t stream) {
  (void)in_sizes; (void)n_in; (void)out_size;
  const float* x      = (const float*)d_in[0];
  const float* W      = (const float*)d_in[1];
  const float* b_caps = (const float*)d_in[2];
  const float* gamma  = (const float*)d_in[3];
  const float* Wq     = (const float*)d_in[4];
  const float* bq     = (const float*)d_in[5];
  const float* Wk     = (const float*)d_in[6];
  const float* bk     = (const float*)d_in[7];
  const float* Wv_in  = (const float*)d_in[8];
  const float* bv_in  = (const float*)d_in[9];
  const float* Wo     = (const float*)d_in[10];
  const float* bo     = (const float*)d_in[11];
  const float* ln_g   = (const float*)d_in[12];
  const float* ln_b   = (const float*)d_in[13];
  float* out = (float*)d_out;
  float* ws  = (float*)d_ws;

  float* xpart = ws + OFF_XPART;
  float* v     = ws + OFF_V;
  float* Wv    = ws + OFF_WV;
  float* bv    = ws + OFF_BV;
  float* y     = ws + OFF_Y;
  float* cs    = ws + OFF_CS;
  float* qkv   = ws + OFF_QKV;
  float* ctx   = ws + OFF_CTX;
  f16*   xf16  = (f16*)(ws + OFF_XF16);
  f16*   wvh   = (f16*)(ws + OFF_WVH);
  float* csp   = ws + OFF_CSP;
  float* yp    = ws + OFF_YP;

  const int usePart = (ws_size >= WS_NEED_PARTIAL) ? 1 : 0;

  // ---- try the single cooperative kernel (grid 256 = 1 block/CU) ----
  hipError_t cerr = hipErrorUnknown;
  if (usePart) {
    int dev = 0, coopAttr = 0;
    hipGetDevice(&dev);
    hipDeviceGetAttribute(&coopAttr, hipDeviceAttributeCooperativeLaunch, dev);
    if (coopAttr) {
      void* args[] = {
          (void*)&x, (void*)&W, (void*)&b_caps, (void*)&Wq, (void*)&bq,
          (void*)&Wk, (void*)&bk, (void*)&Wv_in, (void*)&bv_in, (void*)&Wo,
          (void*)&bo, (void*)&ln_g, (void*)&ln_b, (void*)&gamma,
          (void*)&xpart, (void*)&v, (void*)&Wv, (void*)&wvh, (void*)&bv,
          (void*)&xf16, (void*)&yp, (void*)&csp, (void*)&qkv, (void*)&ctx,
          (void*)&out};
      cerr = hipLaunchCooperativeKernel((const void*)k_caps, dim3(256), dim3(256),
                                        args, 0, stream);
    }
  }
  if (cerr == hipSuccess) return;

  // ---- fallback: verified round-10 multi-kernel pipeline ----
  k_xpart<<<dim3(kB, kXJ), 256, 0, stream>>>(x, xpart, xf16);
  k_sv<<<kB * kC, 256, 0, stream>>>(W, b_caps, xpart, y, cs, yp, csp, v, Wv, wvh, bv,
                                    /*mode=*/0, /*computeWv=*/1, /*accWv=*/0, 0);

  if (!usePart) {
    hipMemsetAsync(y, 0, (size_t)kB * kC * kD * sizeof(float), stream);
    hipMemsetAsync(cs, 0, (size_t)kB * kC * sizeof(float), stream);
  }
  k_route<<<dim3(kB, kChunks), 256, 0, stream>>>(xf16, wvh, bv, y, cs, yp, csp, usePart);
  k_sv<<<kB * kC, 256, 0, stream>>>(W, b_caps, xpart, y, cs, yp, csp, v, Wv, wvh, bv,
                                    /*mode=*/1, /*computeWv=*/1, /*accWv=*/1,
                                    usePart ? kChunks : 0);

  if (!usePart) {
    hipMemsetAsync(y, 0, (size_t)kB * kC * kD * sizeof(float), stream);
    hipMemsetAsync(cs, 0, (size_t)kB * kC * sizeof(float), stream);
  }
  k_route<<<dim3(kB, kChunks), 256, 0, stream>>>(xf16, wvh, bv, y, cs, yp, csp, usePart);
  k_sv<<<kB * kC, 256, 0, stream>>>(W, b_caps, xpart, y, cs, yp, csp, v, Wv, wvh, bv,
                                    /*mode=*/1, /*computeWv=*/0, /*accWv=*/0,
                                    usePart ? kChunks : 0);

  k_qkv<<<dim3(kB, kHeads, 3), 256, 0, stream>>>(v, Wq, bq, Wk, bk, Wv_in, bv_in, qkv);
  k_attn2<<<dim3(kB, kHeads), 256, 0, stream>>>(qkv, ctx);
  k_final<<<kB * kC, 256, 0, stream>>>(ctx, Wo, bo, v, ln_g, ln_b, gamma, out);
}